// Round 4
// baseline (336.341 us; speedup 1.0000x reference)
//
#include <hip/hip_runtime.h>
#include <stdint.h>

typedef unsigned short u16;
typedef __bf16 bf16x8 __attribute__((ext_vector_type(8)));
typedef float f32x4 __attribute__((ext_vector_type(4)));

#define AS1(p) ((const __attribute__((address_space(1))) void*)(p))
#define AS3(p) ((__attribute__((address_space(3))) void*)(p))

__device__ __forceinline__ float b2f(u16 v){
    union { unsigned u; float f; } x; x.u = ((unsigned)v) << 16; return x.f;
}
__device__ __forceinline__ u16 f2b(float f){
    union { float f; unsigned u; } x; x.f = f;
    unsigned r = x.u + 0x7FFFu + ((x.u >> 16) & 1u);
    return (u16)(r >> 16);
}

// ---------------- dtype probe: one block per input tensor (unchanged, proven) ----------------
__global__ __launch_bounds__(256) void probe_kernel(
    const u16* p0,const u16* p1,const u16* p2,const u16* p3,const u16* p4,
    const u16* p5,const u16* p6,const u16* p7,const u16* p8,const u16* p9,
    const u16* p10,const u16* p11,const u16* p12,
    int n0,int n1,int n2,int n3,int n4,int n5,int n6,int n7,int n8,int n9,
    int n10,int n11,int n12, int* flags)
{
    const u16* p; int n;
    switch (blockIdx.x) {
        case 0: p=p0; n=n0; break;   case 1: p=p1; n=n1; break;
        case 2: p=p2; n=n2; break;   case 3: p=p3; n=n3; break;
        case 4: p=p4; n=n4; break;   case 5: p=p5; n=n5; break;
        case 6: p=p6; n=n6; break;   case 7: p=p7; n=n7; break;
        case 8: p=p8; n=n8; break;   case 9: p=p9; n=n9; break;
        case 10: p=p10; n=n10; break; case 11: p=p11; n=n11; break;
        default: p=p12; n=n12; break;
    }
    int pairs = n >> 1; if (pairs > 2048) pairs = 2048;
    int strong = 0, znz = 0, tot = 0;
    for (int k = threadIdx.x; k < pairs; k += 256) {
        u16 lo = p[2*k], hi = p[2*k+1];
        int eh = (hi >> 7) & 0xFF;
        int el = (lo >> 7) & 0xFF;
        if (eh >= 0xF0 || (eh >= 1 && eh <= 0x40)) strong = 1;
        if (el >= 0xF0 || (el >= 1 && el <= 0x40)) strong = 1;
        if (lo == 0 && hi != 0) znz++;
        tot++;
    }
    __shared__ int ss, sz, st;
    if (threadIdx.x == 0) { ss = 0; sz = 0; st = 0; }
    __syncthreads();
    if (strong) atomicOr(&ss, 1);
    if (znz) atomicAdd(&sz, znz);
    atomicAdd(&st, tot);
    __syncthreads();
    if (threadIdx.x == 0) {
        flags[blockIdx.x] = (ss || (2 * sz > st)) ? 1 : 0;
        if (blockIdx.x == 0) flags[15] = 0;
    }
}

// ---------------- convert weight/vector tensors to bf16 (Tf -> f32) in ws (unchanged) -----------
__global__ __launch_bounds__(256) void convert_kernel(
    const void* sWc, const void* sW2, const void* sW1,
    const void* sTa, const void* sBc, const void* sG1, const void* sB1l,
    const void* sTf, const void* sB1, const void* sB2, const void* sG2, const void* sB2l,
    u16* wbase, const int* flags)
{
    int b = blockIdx.x;
    const void* src; u16* dst; int n, fi, lb, tof32 = 0;
    if (b < 128)      { src=sWc; dst=wbase;          n=262144;  fi=2;  lb=b; }
    else if (b < 640) { src=sW2; dst=wbase+262144;   n=1048576; fi=9;  lb=b-128; }
    else if (b >= 643 && b < 651) { src=sW1; dst=wbase+1312256; n=16384; fi=7; lb=b-643; }
    else {
        lb = 0;
        switch (b) {
            case 640: src=sTa;  dst=wbase+1310720; n=512;  fi=1;  break;
            case 641: src=sBc;  dst=wbase+1311232; n=512;  fi=3;  break;
            case 642: src=sB2;  dst=wbase+1311744; n=512;  fi=10; break;
            case 651: src=sB1;  dst=wbase+1328640; n=2048; fi=8;  break;
            case 652: src=sG1;  dst=wbase+1330688; n=512;  fi=4;  break;
            case 653: src=sB1l; dst=wbase+1331200; n=512;  fi=5;  break;
            case 654: src=sG2;  dst=wbase+1331712; n=512;  fi=11; break;
            case 655: src=sB2l; dst=wbase+1332224; n=512;  fi=12; break;
            default:  src=sTf;  dst=wbase+1332736; n=8;    fi=6;  tof32=1; break;
        }
    }
    int i = lb * 256 + threadIdx.x;
    if (i * 8 >= n) return;
    if (tof32) {
        float* fd = (float*)dst;
        if (flags[fi]) {
            const float4* s = (const float4*)src;
            ((float4*)fd)[i*2] = s[i*2]; ((float4*)fd)[i*2+1] = s[i*2+1];
        } else {
            union { uint4 v; u16 h[8]; } sb;
            sb.v = ((const uint4*)src)[i];
            #pragma unroll
            for (int j = 0; j < 8; j++) fd[i*8+j] = b2f(sb.h[j]);
        }
        return;
    }
    if (flags[fi]) {
        const float4* s = (const float4*)src;
        float4 a = s[i*2], c = s[i*2+1];
        union { uint4 v; u16 h[8]; } o;
        o.h[0]=f2b(a.x); o.h[1]=f2b(a.y); o.h[2]=f2b(a.z); o.h[3]=f2b(a.w);
        o.h[4]=f2b(c.x); o.h[5]=f2b(c.y); o.h[6]=f2b(c.z); o.h[7]=f2b(c.w);
        ((uint4*)dst)[i] = o.v;
    } else {
        ((uint4*)dst)[i] = ((const uint4*)src)[i];
    }
}

// ---------------- qgen: q[m,k] = bf16(cos(x[m,k] + theta[k])) — pure streaming ----------------
__global__ __launch_bounds__(256) void qgen_kernel(
    const void* __restrict__ x, const u16* __restrict__ theta,
    u16* __restrict__ q, const int* flags)
{
    const int idx = blockIdx.x * 256 + threadIdx.x;   // octet index, 2,097,152 total
    const int col0 = (idx * 8) & 511;
    union { uint4 v; u16 h[8]; } tb;
    tb.v = *(const uint4*)(theta + col0);
    float xv[8];
    if (flags[0]) {
        const float4* p = (const float4*)x + idx * 2;
        float4 a = p[0], b = p[1];
        xv[0]=a.x; xv[1]=a.y; xv[2]=a.z; xv[3]=a.w;
        xv[4]=b.x; xv[5]=b.y; xv[6]=b.z; xv[7]=b.w;
    } else {
        union { uint4 v; u16 h[8]; } xb;
        xb.v = ((const uint4*)x)[idx];
        #pragma unroll
        for (int e = 0; e < 8; e++) xv[e] = b2f(xb.h[e]);
    }
    union { uint4 v; u16 h[8]; } o;
    #pragma unroll
    for (int e = 0; e < 8; e++) o.h[e] = f2b(__cosf(xv[e] + b2f(tb.h[e])));
    ((uint4*)q)[idx] = o.v;
}

// ======== gemm1: y1[m,n] = sum_k q[m,k]*Wc[n,k] + bc[n] + x[m,n] ========
// Pure bf16 GEMM, m97-family (unchanged from round 3 — left the top-5).
__global__ __launch_bounds__(256, 3) void gemm1_fused(
    const u16* __restrict__ q, const void* __restrict__ x,
    const u16* __restrict__ Wt, const u16* __restrict__ bias,
    u16* __restrict__ dst, int mtiles, const int* flags)
{
    __shared__ __align__(16) u16 As[2][128 * 64];
    __shared__ __align__(16) u16 Bs[2][128 * 64];
    const int K = 512, N = 512;
    const int tid  = threadIdx.x;
    const int lane = tid & 63;
    const int w    = tid >> 6;

    const int blk = blockIdx.x;
    const int xcd = blk & 7;
    const int j   = blk >> 3;
    const int per = mtiles >> 3;
    const int mt  = xcd * per + (j >> 2);
    const int nt  = j & 3;
    const int m0 = mt * 128;
    const int n0 = nt * 128;

    const int srow = lane >> 3;
    const int scol = ((lane & 7) ^ srow) * 8;
    const int wm = (w >> 1) * 64;
    const int wn = (w & 1) * 64;
    const int fr   = lane & 15;
    const int quad = lane >> 4;
    const int fx   = fr & 7;
    const int isf32 = flags[0];

    f32x4 acc[4][4];
    #pragma unroll
    for (int i = 0; i < 4; i++)
        #pragma unroll
        for (int jj = 0; jj < 4; jj++)
            acc[i][jj] = f32x4{0.f, 0.f, 0.f, 0.f};

    const u16* Abase = q  + (size_t)m0 * K + scol;
    const u16* Bbase = Wt + (size_t)n0 * K + scol;

    // prologue: stage buf 0 (A + B)
    #pragma unroll
    for (int i = 0; i < 4; i++) {
        int c = w * 4 + i;
        int row = c * 8 + srow;
        __builtin_amdgcn_global_load_lds(AS1(Abase + (size_t)row * K),
                                         AS3(&As[0][c * 512]), 16, 0, 0);
        __builtin_amdgcn_global_load_lds(AS1(Bbase + (size_t)row * K),
                                         AS3(&Bs[0][c * 512]), 16, 0, 0);
    }

    int cur = 0;
    for (int kt = 0; kt < K; kt += 64) {
        __syncthreads();               // buf[cur] staged (vmcnt drained at barrier)
        if (kt + 64 < K) {             // issue next-tile staging; flies under MFMA phase
            int nxt = cur ^ 1;
            #pragma unroll
            for (int i = 0; i < 4; i++) {
                int c = w * 4 + i;
                int row = c * 8 + srow;
                __builtin_amdgcn_global_load_lds(
                    AS1(Abase + (size_t)row * K + kt + 64),
                    AS3(&As[nxt][c * 512]), 16, 0, 0);
                __builtin_amdgcn_global_load_lds(
                    AS1(Bbase + (size_t)row * K + kt + 64),
                    AS3(&Bs[nxt][c * 512]), 16, 0, 0);
            }
        }
        #pragma unroll
        for (int kk = 0; kk < 2; kk++) {
            bf16x8 af[4], bfr[4];
            #pragma unroll
            for (int mi = 0; mi < 4; mi++)
                af[mi] = *(const bf16x8*)(&As[cur][(wm + mi * 16 + fr) * 64 +
                                          (((kk * 4 + quad) ^ fx) * 8)]);
            #pragma unroll
            for (int ni = 0; ni < 4; ni++)
                bfr[ni] = *(const bf16x8*)(&Bs[cur][(wn + ni * 16 + fr) * 64 +
                                           (((kk * 4 + quad) ^ fx) * 8)]);
            #pragma unroll
            for (int mi = 0; mi < 4; mi++)
                #pragma unroll
                for (int ni = 0; ni < 4; ni++)
                    acc[mi][ni] = __builtin_amdgcn_mfma_f32_16x16x32_bf16(
                        af[mi], bfr[ni], acc[mi][ni], 0, 0, 0);
        }
        cur ^= 1;
    }

    #pragma unroll
    for (int mi = 0; mi < 4; mi++) {
        #pragma unroll
        for (int ni = 0; ni < 4; ni++) {
            int n = n0 + wn + ni * 16 + fr;
            float bn = b2f(bias[n]);
            #pragma unroll
            for (int r = 0; r < 4; r++) {
                int m = m0 + wm + mi * 16 + quad * 4 + r;
                float rv = isf32 ? ((const float*)x)[(size_t)m * N + n]
                                 : b2f(((const u16*)x)[(size_t)m * N + n]);
                dst[(size_t)m * N + n] = f2b(acc[mi][ni][r] + bn + rv);
            }
        }
    }
}

// ======== gemm2: z[m,n] = sum_k relu(fq[m,:8]@W1[k,:8]+b1[k])*W2[n,k] + b2[n] + x1[m,n] ========
// h A-FRAGMENTS GENERATED DIRECTLY IN REGISTERS — no As LDS tile, no h-gen barrier, no
// bank conflicts. Key identity: h-gen mfma(W1_rows, fq_cols, b1) output layout
// (col=lane&15=m, row=(lane>>4)*4+r=k) IS the main-MFMA A-frag layout (row=lane&15=m,
// k=(lane>>4)*8+e) when W1 rows are fed interleaved: MFMA g=2*kk+half uses W1 row
// k(i) = kt + kk*32 + (i>>2)*8 + half*4 + (i&3), so lane gets contiguous k-octet
// quad*8+0..7 from the (half=0, half=1) pair. k is fully reduced -> row order is free.
// Each wave covers its OWN 64-row m-range (2x h-gen redundancy, ~1/3 of main MFMA work).
// ONE barrier per K-step; LDS = Bs dbuf 32KB only.
__global__ __launch_bounds__(256, 3) void gemm2_fused(
    const u16* __restrict__ fq, const u16* __restrict__ W1, const u16* __restrict__ b1,
    const u16* __restrict__ Wt, const u16* __restrict__ bias,
    const u16* __restrict__ res, u16* __restrict__ dst, int mtiles)
{
    __shared__ __align__(16) u16 Bs[2][128 * 64];
    const int K = 2048, N = 512;
    const int tid  = threadIdx.x;
    const int lane = tid & 63;
    const int w    = tid >> 6;

    const int blk = blockIdx.x;
    const int xcd = blk & 7;
    const int j   = blk >> 3;
    const int per = mtiles >> 3;
    const int mt  = xcd * per + (j >> 2);
    const int nt  = j & 3;
    const int m0 = mt * 128;
    const int n0 = nt * 128;

    const int srow = lane >> 3;
    const int scol = ((lane & 7) ^ srow) * 8;
    const int wm = (w >> 1) * 64;
    const int wn = (w & 1) * 64;
    const int fr   = lane & 15;
    const int quad = lane >> 4;
    const int fx   = fr & 7;

    // fq B-frags for h-gen: wave's own 4 m-subtiles (m = m0+wm+mi*16+fr), quad0 holds data.
    bf16x8 fqf[4];
    #pragma unroll
    for (int mi = 0; mi < 4; mi++) {
        union { uint4 v; bf16x8 b; } z; z.v = uint4{0,0,0,0};
        if (quad == 0) z.v = *(const uint4*)(fq + (size_t)(m0 + wm + mi * 16 + fr) * 8);
        fqf[mi] = z.b;
    }

    // interleaved W1-row index for h-gen MFMA g (quad0 lanes supply A rows):
    const int krow = ((fr >> 2) * 8) + (fr & 3);      // + kt + (g>>1)*32 + (g&1)*4

    // W1 frags + b1 frags for kt=0
    union { uint4 v; bf16x8 b; } w1f[4];
    uint2 b1f[4];
    #pragma unroll
    for (int g = 0; g < 4; g++) {
        w1f[g].v = uint4{0,0,0,0};
        if (quad == 0)
            w1f[g].v = *(const uint4*)(W1 + (size_t)((g >> 1) * 32 + (g & 1) * 4 + krow) * 8);
        b1f[g] = *(const uint2*)(b1 + (g >> 1) * 32 + (g & 1) * 4 + quad * 8);
    }

    f32x4 acc[4][4];
    #pragma unroll
    for (int i = 0; i < 4; i++)
        #pragma unroll
        for (int jj = 0; jj < 4; jj++)
            acc[i][jj] = f32x4{0.f, 0.f, 0.f, 0.f};

    const u16* Bbase = Wt + (size_t)n0 * K + scol;
    #pragma unroll
    for (int i = 0; i < 4; i++) {
        int c = w * 4 + i;
        int row = c * 8 + srow;
        __builtin_amdgcn_global_load_lds(AS1(Bbase + (size_t)row * K),
                                         AS3(&Bs[0][c * 512]), 16, 0, 0);
    }

    int cur = 0;
    for (int kt = 0; kt < K; kt += 64) {
        __syncthreads();               // Bs[cur] staged, w1f/b1f for this kt ready
        if (kt + 64 < K) {             // issue next Bs staging; flies under compute
            int nxt = cur ^ 1;
            #pragma unroll
            for (int i = 0; i < 4; i++) {
                int c = w * 4 + i;
                int row = c * 8 + srow;
                __builtin_amdgcn_global_load_lds(
                    AS1(Bbase + (size_t)row * K + kt + 64),
                    AS3(&Bs[nxt][c * 512]), 16, 0, 0);
            }
        }
        #pragma unroll
        for (int kk = 0; kk < 2; kk++) {
            bf16x8 bfr[4];
            #pragma unroll
            for (int ni = 0; ni < 4; ni++)
                bfr[ni] = *(const bf16x8*)(&Bs[cur][(wn + ni * 16 + fr) * 64 +
                                           (((kk * 4 + quad) ^ fx) * 8)]);
            const u16* pb0 = (const u16*)&b1f[kk * 2 + 0];
            const u16* pb1 = (const u16*)&b1f[kk * 2 + 1];
            f32x4 c0 = {b2f(pb0[0]), b2f(pb0[1]), b2f(pb0[2]), b2f(pb0[3])};
            f32x4 c1 = {b2f(pb1[0]), b2f(pb1[1]), b2f(pb1[2]), b2f(pb1[3])};
            #pragma unroll
            for (int mi = 0; mi < 4; mi++) {
                f32x4 hv0 = __builtin_amdgcn_mfma_f32_16x16x32_bf16(
                    w1f[kk * 2 + 0].b, fqf[mi], c0, 0, 0, 0);
                f32x4 hv1 = __builtin_amdgcn_mfma_f32_16x16x32_bf16(
                    w1f[kk * 2 + 1].b, fqf[mi], c1, 0, 0, 0);
                bf16x8 af;
                #pragma unroll
                for (int r = 0; r < 4; r++) {
                    af[r]     = (__bf16)fmaxf(hv0[r], 0.f);
                    af[4 + r] = (__bf16)fmaxf(hv1[r], 0.f);
                }
                #pragma unroll
                for (int ni = 0; ni < 4; ni++)
                    acc[mi][ni] = __builtin_amdgcn_mfma_f32_16x16x32_bf16(
                        af, bfr[ni], acc[mi][ni], 0, 0, 0);
            }
        }
        // prefetch next kt's W1/b1 frags (tiny, L1-resident; lands during barrier+ds_reads)
        if (kt + 64 < K) {
            #pragma unroll
            for (int g = 0; g < 4; g++) {
                if (quad == 0)
                    w1f[g].v = *(const uint4*)(W1 +
                        (size_t)(kt + 64 + (g >> 1) * 32 + (g & 1) * 4 + krow) * 8);
                b1f[g] = *(const uint2*)(b1 + kt + 64 + (g >> 1) * 32 + (g & 1) * 4 + quad * 8);
            }
        }
        cur ^= 1;
    }

    #pragma unroll
    for (int mi = 0; mi < 4; mi++) {
        #pragma unroll
        for (int ni = 0; ni < 4; ni++) {
            int n = n0 + wn + ni * 16 + fr;
            float bn = b2f(bias[n]);
            #pragma unroll
            for (int r = 0; r < 4; r++) {
                int m = m0 + wm + mi * 16 + quad * 4 + r;
                float rv = b2f(res[(size_t)m * N + n]);
                dst[(size_t)m * N + n] = f2b(acc[mi][ni][r] + bn + rv);
            }
        }
    }
}

// ------- ln1: x1 = LN(y1)*g+b; fq = cos(x1[:,:8]+tf)  (h generation moved into gemm2) -------
__global__ __launch_bounds__(512) void ln1_kernel(
    const u16* __restrict__ y1, const u16* __restrict__ g, const u16* __restrict__ b,
    const float* __restrict__ tf, u16* __restrict__ x1, u16* __restrict__ fqout)
{
    __shared__ __align__(16) float xs8[64][8];
    const int t = threadIdx.x;
    const int wv = t >> 6, l = t & 63;
    const size_t rbase = (size_t)blockIdx.x * 64;

    union { uint4 v; u16 s[8]; } gb, bb;
    gb.v = *(const uint4*)(g + l * 8);
    bb.v = *(const uint4*)(b + l * 8);

    #pragma unroll
    for (int i = 0; i < 8; i++) {
        int lr = wv * 8 + i;
        union { uint4 v; u16 s[8]; } yb;
        yb.v = ((const uint4*)(y1 + (rbase + lr) * 512))[l];
        float xv[8], s = 0.f, ss = 0.f;
        #pragma unroll
        for (int jj = 0; jj < 8; jj++) {
            xv[jj] = b2f(yb.s[jj]); s += xv[jj]; ss += xv[jj] * xv[jj];
        }
        #pragma unroll
        for (int o = 32; o > 0; o >>= 1) { s += __shfl_down(s, o); ss += __shfl_down(ss, o); }
        s = __shfl(s, 0); ss = __shfl(ss, 0);
        float mu = s * (1.f / 512.f);
        float rs = rsqrtf(ss * (1.f / 512.f) - mu * mu + 1e-5f);
        union { uint4 v; u16 s[8]; } ob;
        float xn[8];
        #pragma unroll
        for (int jj = 0; jj < 8; jj++) {
            xn[jj] = (xv[jj] - mu) * rs * b2f(gb.s[jj]) + b2f(bb.s[jj]);
            ob.s[jj] = f2b(xn[jj]);
        }
        ((uint4*)(x1 + (rbase + lr) * 512))[l] = ob.v;
        if (l == 0) {
            #pragma unroll
            for (int jj = 0; jj < 8; jj++) xs8[lr][jj] = xn[jj];
        }
    }
    __syncthreads();
    {
        int r = t >> 3, jj = t & 7;
        fqout[(rbase + r) * 8 + jj] = f2b(__cosf(xs8[r][jj] + tf[jj]));
    }
}

// ---------------- ln2: 1 row per wave, output dtype per flags[0] ----------------
__global__ __launch_bounds__(256) void ln2_kernel(
    const u16* __restrict__ z, const u16* __restrict__ g, const u16* __restrict__ b,
    void* __restrict__ out, const int* flags)
{
    const int t = threadIdx.x;
    const int wv = t >> 6, l = t & 63;
    const size_t row = (size_t)blockIdx.x * 4 + wv;

    union { uint4 v; u16 s[8]; } zb, gb, bb;
    zb.v = ((const uint4*)(z + row * 512))[l];
    gb.v = *(const uint4*)(g + l * 8);
    bb.v = *(const uint4*)(b + l * 8);
    float xv[8], s = 0.f, ss = 0.f;
    #pragma unroll
    for (int jj = 0; jj < 8; jj++) { xv[jj] = b2f(zb.s[jj]); s += xv[jj]; ss += xv[jj]*xv[jj]; }
    #pragma unroll
    for (int o = 32; o > 0; o >>= 1) { s += __shfl_down(s, o); ss += __shfl_down(ss, o); }
    s = __shfl(s, 0); ss = __shfl(ss, 0);
    float mu = s * (1.f / 512.f);
    float rs = rsqrtf(ss * (1.f / 512.f) - mu * mu + 1e-5f);
    float xn[8];
    #pragma unroll
    for (int jj = 0; jj < 8; jj++)
        xn[jj] = (xv[jj] - mu) * rs * b2f(gb.s[jj]) + b2f(bb.s[jj]);
    if (flags[0]) {
        float* po = (float*)out + row * 512 + l * 8;
        float4 o0{xn[0],xn[1],xn[2],xn[3]}, o1{xn[4],xn[5],xn[6],xn[7]};
        *(float4*)po = o0; *(float4*)(po + 4) = o1;
    } else {
        union { uint4 v; u16 s[8]; } ob;
        #pragma unroll
        for (int jj = 0; jj < 8; jj++) ob.s[jj] = f2b(xn[jj]);
        ((uint4*)((u16*)out + row * 512))[l] = ob.v;
    }
}

extern "C" void kernel_launch(void* const* d_in, const int* in_sizes, int n_in,
                              void* d_out, int out_size, void* d_ws, size_t ws_size,
                              hipStream_t stream)
{
    u16* ws16 = (u16*)d_ws;
    // ws (u16 elems): W [0,1332752) | flags @1332752 | fq @1332800 (262144)
    //                 x1 @1594944 (16.7M) | y1/z @18372160 (16.7M)  => ~70.3 MB total
    // q (cos(x+theta), bf16) ALIASES the x1 region: q live [qgen, gemm1); x1 written by ln1 after.
    u16* W     = ws16;
    int* flags = (int*)(ws16 + 1332752);
    u16* fq  = ws16 + 1332800;
    u16* x1  = ws16 + 1594944;
    u16* q   = x1;
    u16* y1  = ws16 + 18372160;
    u16* z   = y1;                  // y1 rows dead after ln1; z overwrites

    const u16*  wWc  = W;
    const u16*  wW2  = W + 262144;
    const u16*  wTa  = W + 1310720;
    const u16*  wBc  = W + 1311232;
    const u16*  wB2  = W + 1311744;
    const u16*  wW1  = W + 1312256;
    const u16*  wB1  = W + 1328640;
    const u16*  wG1  = W + 1330688;
    const u16*  wB1l = W + 1331200;
    const u16*  wG2  = W + 1331712;
    const u16*  wB2l = W + 1332224;
    const float* wTf = (const float*)(W + 1332736);

    probe_kernel<<<13, 256, 0, stream>>>(
        (const u16*)d_in[0], (const u16*)d_in[1], (const u16*)d_in[2],
        (const u16*)d_in[3], (const u16*)d_in[4], (const u16*)d_in[5],
        (const u16*)d_in[6], (const u16*)d_in[7], (const u16*)d_in[8],
        (const u16*)d_in[9], (const u16*)d_in[10], (const u16*)d_in[11],
        (const u16*)d_in[12],
        in_sizes[0], in_sizes[1], in_sizes[2], in_sizes[3], in_sizes[4],
        in_sizes[5], in_sizes[6], in_sizes[7], in_sizes[8], in_sizes[9],
        in_sizes[10], in_sizes[11], in_sizes[12], flags);

    convert_kernel<<<657, 256, 0, stream>>>(
        d_in[2], d_in[9], d_in[7], d_in[1], d_in[3], d_in[4], d_in[5],
        d_in[6], d_in[8], d_in[10], d_in[11], d_in[12], (u16*)W, flags);

    qgen_kernel<<<8192, 256, 0, stream>>>(d_in[0], wTa, q, flags);

    gemm1_fused<<<1024, 256, 0, stream>>>(
        q, d_in[0], wWc, wBc, y1, 256, flags);

    ln1_kernel<<<512, 512, 0, stream>>>(y1, wG1, wB1l, wTf, x1, fq);

    gemm2_fused<<<1024, 256, 0, stream>>>(
        fq, wW1, wB1, wW2, wB2, x1, z, 256);

    ln2_kernel<<<8192, 256, 0, stream>>>(z, wG2, wB2l, d_out, flags);
}

// Round 5
// 316.353 us; speedup vs baseline: 1.0632x; 1.0632x over previous
//
#include <hip/hip_runtime.h>
#include <stdint.h>

typedef unsigned short u16;
typedef __bf16 bf16x8 __attribute__((ext_vector_type(8)));
typedef float f32x4 __attribute__((ext_vector_type(4)));

#define AS1(p) ((const __attribute__((address_space(1))) void*)(p))
#define AS3(p) ((__attribute__((address_space(3))) void*)(p))

__device__ __forceinline__ float b2f(u16 v){
    union { unsigned u; float f; } x; x.u = ((unsigned)v) << 16; return x.f;
}
__device__ __forceinline__ u16 f2b(float f){
    union { float f; unsigned u; } x; x.f = f;
    unsigned r = x.u + 0x7FFFu + ((x.u >> 16) & 1u);
    return (u16)(r >> 16);
}

// ---------------- dtype probe: one block per input tensor (unchanged, proven) ----------------
__global__ __launch_bounds__(256) void probe_kernel(
    const u16* p0,const u16* p1,const u16* p2,const u16* p3,const u16* p4,
    const u16* p5,const u16* p6,const u16* p7,const u16* p8,const u16* p9,
    const u16* p10,const u16* p11,const u16* p12,
    int n0,int n1,int n2,int n3,int n4,int n5,int n6,int n7,int n8,int n9,
    int n10,int n11,int n12, int* flags)
{
    const u16* p; int n;
    switch (blockIdx.x) {
        case 0: p=p0; n=n0; break;   case 1: p=p1; n=n1; break;
        case 2: p=p2; n=n2; break;   case 3: p=p3; n=n3; break;
        case 4: p=p4; n=n4; break;   case 5: p=p5; n=n5; break;
        case 6: p=p6; n=n6; break;   case 7: p=p7; n=n7; break;
        case 8: p=p8; n=n8; break;   case 9: p=p9; n=n9; break;
        case 10: p=p10; n=n10; break; case 11: p=p11; n=n11; break;
        default: p=p12; n=n12; break;
    }
    int pairs = n >> 1; if (pairs > 2048) pairs = 2048;
    int strong = 0, znz = 0, tot = 0;
    for (int k = threadIdx.x; k < pairs; k += 256) {
        u16 lo = p[2*k], hi = p[2*k+1];
        int eh = (hi >> 7) & 0xFF;
        int el = (lo >> 7) & 0xFF;
        if (eh >= 0xF0 || (eh >= 1 && eh <= 0x40)) strong = 1;
        if (el >= 0xF0 || (el >= 1 && el <= 0x40)) strong = 1;
        if (lo == 0 && hi != 0) znz++;
        tot++;
    }
    __shared__ int ss, sz, st;
    if (threadIdx.x == 0) { ss = 0; sz = 0; st = 0; }
    __syncthreads();
    if (strong) atomicOr(&ss, 1);
    if (znz) atomicAdd(&sz, znz);
    atomicAdd(&st, tot);
    __syncthreads();
    if (threadIdx.x == 0) {
        flags[blockIdx.x] = (ss || (2 * sz > st)) ? 1 : 0;
        if (blockIdx.x == 0) flags[15] = 0;
    }
}

// ---------------- convert weight/vector tensors to bf16 (Tf -> f32) in ws (unchanged) -----------
__global__ __launch_bounds__(256) void convert_kernel(
    const void* sWc, const void* sW2, const void* sW1,
    const void* sTa, const void* sBc, const void* sG1, const void* sB1l,
    const void* sTf, const void* sB1, const void* sB2, const void* sG2, const void* sB2l,
    u16* wbase, const int* flags)
{
    int b = blockIdx.x;
    const void* src; u16* dst; int n, fi, lb, tof32 = 0;
    if (b < 128)      { src=sWc; dst=wbase;          n=262144;  fi=2;  lb=b; }
    else if (b < 640) { src=sW2; dst=wbase+262144;   n=1048576; fi=9;  lb=b-128; }
    else if (b >= 643 && b < 651) { src=sW1; dst=wbase+1312256; n=16384; fi=7; lb=b-643; }
    else {
        lb = 0;
        switch (b) {
            case 640: src=sTa;  dst=wbase+1310720; n=512;  fi=1;  break;
            case 641: src=sBc;  dst=wbase+1311232; n=512;  fi=3;  break;
            case 642: src=sB2;  dst=wbase+1311744; n=512;  fi=10; break;
            case 651: src=sB1;  dst=wbase+1328640; n=2048; fi=8;  break;
            case 652: src=sG1;  dst=wbase+1330688; n=512;  fi=4;  break;
            case 653: src=sB1l; dst=wbase+1331200; n=512;  fi=5;  break;
            case 654: src=sG2;  dst=wbase+1331712; n=512;  fi=11; break;
            case 655: src=sB2l; dst=wbase+1332224; n=512;  fi=12; break;
            default:  src=sTf;  dst=wbase+1332736; n=8;    fi=6;  tof32=1; break;
        }
    }
    int i = lb * 256 + threadIdx.x;
    if (i * 8 >= n) return;
    if (tof32) {
        float* fd = (float*)dst;
        if (flags[fi]) {
            const float4* s = (const float4*)src;
            ((float4*)fd)[i*2] = s[i*2]; ((float4*)fd)[i*2+1] = s[i*2+1];
        } else {
            union { uint4 v; u16 h[8]; } sb;
            sb.v = ((const uint4*)src)[i];
            #pragma unroll
            for (int j = 0; j < 8; j++) fd[i*8+j] = b2f(sb.h[j]);
        }
        return;
    }
    if (flags[fi]) {
        const float4* s = (const float4*)src;
        float4 a = s[i*2], c = s[i*2+1];
        union { uint4 v; u16 h[8]; } o;
        o.h[0]=f2b(a.x); o.h[1]=f2b(a.y); o.h[2]=f2b(a.z); o.h[3]=f2b(a.w);
        o.h[4]=f2b(c.x); o.h[5]=f2b(c.y); o.h[6]=f2b(c.z); o.h[7]=f2b(c.w);
        ((uint4*)dst)[i] = o.v;
    } else {
        ((uint4*)dst)[i] = ((const uint4*)src)[i];
    }
}

// ---------------- qgen: q[m,k] = bf16(cos(x[m,k] + theta[k])) — pure streaming ----------------
__global__ __launch_bounds__(256) void qgen_kernel(
    const void* __restrict__ x, const u16* __restrict__ theta,
    u16* __restrict__ q, const int* flags)
{
    const int idx = blockIdx.x * 256 + threadIdx.x;   // octet index, 2,097,152 total
    const int col0 = (idx * 8) & 511;
    union { uint4 v; u16 h[8]; } tb;
    tb.v = *(const uint4*)(theta + col0);
    float xv[8];
    if (flags[0]) {
        const float4* p = (const float4*)x + idx * 2;
        float4 a = p[0], b = p[1];
        xv[0]=a.x; xv[1]=a.y; xv[2]=a.z; xv[3]=a.w;
        xv[4]=b.x; xv[5]=b.y; xv[6]=b.z; xv[7]=b.w;
    } else {
        union { uint4 v; u16 h[8]; } xb;
        xb.v = ((const uint4*)x)[idx];
        #pragma unroll
        for (int e = 0; e < 8; e++) xv[e] = b2f(xb.h[e]);
    }
    union { uint4 v; u16 h[8]; } o;
    #pragma unroll
    for (int e = 0; e < 8; e++) o.h[e] = f2b(__cosf(xv[e] + b2f(tb.h[e])));
    ((uint4*)q)[idx] = o.v;
}

// ======== gemm1: y1[m,n] = sum_k q[m,k]*Wc[n,k] + bc[n] + x[m,n] ========
// Pure bf16 GEMM, m97-family (unchanged — left the top-5).
__global__ __launch_bounds__(256, 3) void gemm1_fused(
    const u16* __restrict__ q, const void* __restrict__ x,
    const u16* __restrict__ Wt, const u16* __restrict__ bias,
    u16* __restrict__ dst, int mtiles, const int* flags)
{
    __shared__ __align__(16) u16 As[2][128 * 64];
    __shared__ __align__(16) u16 Bs[2][128 * 64];
    const int K = 512, N = 512;
    const int tid  = threadIdx.x;
    const int lane = tid & 63;
    const int w    = tid >> 6;

    const int blk = blockIdx.x;
    const int xcd = blk & 7;
    const int j   = blk >> 3;
    const int per = mtiles >> 3;
    const int mt  = xcd * per + (j >> 2);
    const int nt  = j & 3;
    const int m0 = mt * 128;
    const int n0 = nt * 128;

    const int srow = lane >> 3;
    const int scol = ((lane & 7) ^ srow) * 8;
    const int wm = (w >> 1) * 64;
    const int wn = (w & 1) * 64;
    const int fr   = lane & 15;
    const int quad = lane >> 4;
    const int fx   = fr & 7;
    const int isf32 = flags[0];

    f32x4 acc[4][4];
    #pragma unroll
    for (int i = 0; i < 4; i++)
        #pragma unroll
        for (int jj = 0; jj < 4; jj++)
            acc[i][jj] = f32x4{0.f, 0.f, 0.f, 0.f};

    const u16* Abase = q  + (size_t)m0 * K + scol;
    const u16* Bbase = Wt + (size_t)n0 * K + scol;

    // prologue: stage buf 0 (A + B)
    #pragma unroll
    for (int i = 0; i < 4; i++) {
        int c = w * 4 + i;
        int row = c * 8 + srow;
        __builtin_amdgcn_global_load_lds(AS1(Abase + (size_t)row * K),
                                         AS3(&As[0][c * 512]), 16, 0, 0);
        __builtin_amdgcn_global_load_lds(AS1(Bbase + (size_t)row * K),
                                         AS3(&Bs[0][c * 512]), 16, 0, 0);
    }

    int cur = 0;
    for (int kt = 0; kt < K; kt += 64) {
        __syncthreads();               // buf[cur] staged (vmcnt drained at barrier)
        if (kt + 64 < K) {             // issue next-tile staging; flies under MFMA phase
            int nxt = cur ^ 1;
            #pragma unroll
            for (int i = 0; i < 4; i++) {
                int c = w * 4 + i;
                int row = c * 8 + srow;
                __builtin_amdgcn_global_load_lds(
                    AS1(Abase + (size_t)row * K + kt + 64),
                    AS3(&As[nxt][c * 512]), 16, 0, 0);
                __builtin_amdgcn_global_load_lds(
                    AS1(Bbase + (size_t)row * K + kt + 64),
                    AS3(&Bs[nxt][c * 512]), 16, 0, 0);
            }
        }
        #pragma unroll
        for (int kk = 0; kk < 2; kk++) {
            bf16x8 af[4], bfr[4];
            #pragma unroll
            for (int mi = 0; mi < 4; mi++)
                af[mi] = *(const bf16x8*)(&As[cur][(wm + mi * 16 + fr) * 64 +
                                          (((kk * 4 + quad) ^ fx) * 8)]);
            #pragma unroll
            for (int ni = 0; ni < 4; ni++)
                bfr[ni] = *(const bf16x8*)(&Bs[cur][(wn + ni * 16 + fr) * 64 +
                                           (((kk * 4 + quad) ^ fx) * 8)]);
            #pragma unroll
            for (int mi = 0; mi < 4; mi++)
                #pragma unroll
                for (int ni = 0; ni < 4; ni++)
                    acc[mi][ni] = __builtin_amdgcn_mfma_f32_16x16x32_bf16(
                        af[mi], bfr[ni], acc[mi][ni], 0, 0, 0);
        }
        cur ^= 1;
    }

    #pragma unroll
    for (int mi = 0; mi < 4; mi++) {
        #pragma unroll
        for (int ni = 0; ni < 4; ni++) {
            int n = n0 + wn + ni * 16 + fr;
            float bn = b2f(bias[n]);
            #pragma unroll
            for (int r = 0; r < 4; r++) {
                int m = m0 + wm + mi * 16 + quad * 4 + r;
                float rv = isf32 ? ((const float*)x)[(size_t)m * N + n]
                                 : b2f(((const u16*)x)[(size_t)m * N + n]);
                dst[(size_t)m * N + n] = f2b(acc[mi][ni][r] + bn + rv);
            }
        }
    }
}

// ======== gemm2: z[m,n] = sum_k relu(fq[m,:8]@W1[k,:8]+b1[k])*W2[n,k] + b2[n] + x1[m,n] ========
// BM=128 x BN=512 (FULL N per block) x BK=64, 8 waves, each wave owns 64m x 128n.
// Kills the nt dimension: round-4's h-gen (+relu/cvt VALU) was duplicated 4x across
// nt blocks (PMC: VALUBusy 51% = ~61us of VALU work, the real bottleneck). Same
// register h-gen identity as round 4 (passed harness), now amortized over 2x the
// main MFMA per wave; total h-gen MFMA and h-cvt VALU halve.
// LDS = Bs dbuf 128KB (no As); 1 barrier/K-step; grid 256 = 1 block/CU.
// launch_bounds(512,2): cap 256 regs (peak liveness ~230, bfr in PAIRS to stay under).
__global__ __launch_bounds__(512, 2) void gemm2_fused(
    const u16* __restrict__ fq, const u16* __restrict__ W1, const u16* __restrict__ b1,
    const u16* __restrict__ Wt, const u16* __restrict__ bias,
    const u16* __restrict__ res, u16* __restrict__ dst, int mtiles)
{
    __shared__ __align__(16) u16 Bs[2][512 * 64];
    const int K = 2048, N = 512;
    const int tid  = threadIdx.x;
    const int lane = tid & 63;
    const int w    = tid >> 6;

    const int m0 = blockIdx.x * 128;

    const int srow = lane >> 3;
    const int scol = ((lane & 7) ^ srow) * 8;
    const int wm = (w >> 2) * 64;          // 2 waves per 64-row m-range
    const int wn = (w & 3) * 128;          // 4 n-positions of 128
    const int fr   = lane & 15;
    const int quad = lane >> 4;
    const int fx   = fr & 7;

    // fq B-frags for h-gen: wave's own 4 m-subtiles (m = m0+wm+mi*16+fr), quad0 holds data.
    bf16x8 fqf[4];
    #pragma unroll
    for (int mi = 0; mi < 4; mi++) {
        union { uint4 v; bf16x8 b; } z; z.v = uint4{0,0,0,0};
        if (quad == 0) z.v = *(const uint4*)(fq + (size_t)(m0 + wm + mi * 16 + fr) * 8);
        fqf[mi] = z.b;
    }

    // interleaved W1-row index for h-gen MFMA g (quad0 lanes supply A rows):
    const int krow = ((fr >> 2) * 8) + (fr & 3);      // + kt + (g>>1)*32 + (g&1)*4

    // W1 frags + b1 frags for kt=0 (identical to round-4 proven layout)
    union { uint4 v; bf16x8 b; } w1f[4];
    uint2 b1f[4];
    #pragma unroll
    for (int g = 0; g < 4; g++) {
        w1f[g].v = uint4{0,0,0,0};
        if (quad == 0)
            w1f[g].v = *(const uint4*)(W1 + (size_t)((g >> 1) * 32 + (g & 1) * 4 + krow) * 8);
        b1f[g] = *(const uint2*)(b1 + (g >> 1) * 32 + (g & 1) * 4 + quad * 8);
    }

    f32x4 acc[4][8];
    #pragma unroll
    for (int i = 0; i < 4; i++)
        #pragma unroll
        for (int jj = 0; jj < 8; jj++)
            acc[i][jj] = f32x4{0.f, 0.f, 0.f, 0.f};

    // B staging: rows are n (0..511), full N. 8 row-groups of 8 per wave-issue set.
    const u16* Bbase = Wt + scol;
    #pragma unroll
    for (int i = 0; i < 8; i++) {
        int c = w * 8 + i;
        int row = c * 8 + srow;
        __builtin_amdgcn_global_load_lds(AS1(Bbase + (size_t)row * K),
                                         AS3(&Bs[0][c * 512]), 16, 0, 0);
    }

    int cur = 0;
    for (int kt = 0; kt < K; kt += 64) {
        __syncthreads();               // Bs[cur] staged, w1f/b1f for this kt ready
        if (kt + 64 < K) {             // issue next Bs staging; flies under compute
            int nxt = cur ^ 1;
            #pragma unroll
            for (int i = 0; i < 8; i++) {
                int c = w * 8 + i;
                int row = c * 8 + srow;
                __builtin_amdgcn_global_load_lds(
                    AS1(Bbase + (size_t)row * K + kt + 64),
                    AS3(&Bs[nxt][c * 512]), 16, 0, 0);
            }
        }
        #pragma unroll
        for (int kk = 0; kk < 2; kk++) {
            // ---- h-gen: af for all 4 mi (register-direct, round-4 identity) ----
            const u16* pb0 = (const u16*)&b1f[kk * 2 + 0];
            const u16* pb1 = (const u16*)&b1f[kk * 2 + 1];
            f32x4 c0 = {b2f(pb0[0]), b2f(pb0[1]), b2f(pb0[2]), b2f(pb0[3])};
            f32x4 c1 = {b2f(pb1[0]), b2f(pb1[1]), b2f(pb1[2]), b2f(pb1[3])};
            bf16x8 af[4];
            #pragma unroll
            for (int mi = 0; mi < 4; mi++) {
                f32x4 hv0 = __builtin_amdgcn_mfma_f32_16x16x32_bf16(
                    w1f[kk * 2 + 0].b, fqf[mi], c0, 0, 0, 0);
                f32x4 hv1 = __builtin_amdgcn_mfma_f32_16x16x32_bf16(
                    w1f[kk * 2 + 1].b, fqf[mi], c1, 0, 0, 0);
                #pragma unroll
                for (int r = 0; r < 4; r++) {
                    af[mi][r]     = (__bf16)fmaxf(hv0[r], 0.f);
                    af[mi][4 + r] = (__bf16)fmaxf(hv1[r], 0.f);
                }
            }
            // ---- main MFMA over the wave's 128 n, in ni PAIRS (register budget) ----
            #pragma unroll
            for (int np = 0; np < 4; np++) {
                bf16x8 bfr[2];
                #pragma unroll
                for (int ni = 0; ni < 2; ni++)
                    bfr[ni] = *(const bf16x8*)(&Bs[cur][(wn + (np * 2 + ni) * 16 + fr) * 64 +
                                               (((kk * 4 + quad) ^ fx) * 8)]);
                #pragma unroll
                for (int mi = 0; mi < 4; mi++)
                    #pragma unroll
                    for (int ni = 0; ni < 2; ni++)
                        acc[mi][np * 2 + ni] = __builtin_amdgcn_mfma_f32_16x16x32_bf16(
                            af[mi], bfr[ni], acc[mi][np * 2 + ni], 0, 0, 0);
            }
        }
        // prefetch next kt's W1/b1 frags (tiny, L1/L2-resident)
        if (kt + 64 < K) {
            #pragma unroll
            for (int g = 0; g < 4; g++) {
                if (quad == 0)
                    w1f[g].v = *(const uint4*)(W1 +
                        (size_t)(kt + 64 + (g >> 1) * 32 + (g & 1) * 4 + krow) * 8);
                b1f[g] = *(const uint2*)(b1 + kt + 64 + (g >> 1) * 32 + (g & 1) * 4 + quad * 8);
            }
        }
        cur ^= 1;
    }

    #pragma unroll
    for (int mi = 0; mi < 4; mi++) {
        #pragma unroll
        for (int nq = 0; nq < 8; nq++) {
            int n = wn + nq * 16 + fr;
            float bn = b2f(bias[n]);
            #pragma unroll
            for (int r = 0; r < 4; r++) {
                int m = m0 + wm + mi * 16 + quad * 4 + r;
                float rv = b2f(res[(size_t)m * N + n]);
                dst[(size_t)m * N + n] = f2b(acc[mi][nq][r] + bn + rv);
            }
        }
    }
}

// ------- ln1: x1 = LN(y1)*g+b; fq = cos(x1[:,:8]+tf)  (h generation stays in gemm2) -------
__global__ __launch_bounds__(512) void ln1_kernel(
    const u16* __restrict__ y1, const u16* __restrict__ g, const u16* __restrict__ b,
    const float* __restrict__ tf, u16* __restrict__ x1, u16* __restrict__ fqout)
{
    __shared__ __align__(16) float xs8[64][8];
    const int t = threadIdx.x;
    const int wv = t >> 6, l = t & 63;
    const size_t rbase = (size_t)blockIdx.x * 64;

    union { uint4 v; u16 s[8]; } gb, bb;
    gb.v = *(const uint4*)(g + l * 8);
    bb.v = *(const uint4*)(b + l * 8);

    #pragma unroll
    for (int i = 0; i < 8; i++) {
        int lr = wv * 8 + i;
        union { uint4 v; u16 s[8]; } yb;
        yb.v = ((const uint4*)(y1 + (rbase + lr) * 512))[l];
        float xv[8], s = 0.f, ss = 0.f;
        #pragma unroll
        for (int jj = 0; jj < 8; jj++) {
            xv[jj] = b2f(yb.s[jj]); s += xv[jj]; ss += xv[jj] * xv[jj];
        }
        #pragma unroll
        for (int o = 32; o > 0; o >>= 1) { s += __shfl_down(s, o); ss += __shfl_down(ss, o); }
        s = __shfl(s, 0); ss = __shfl(ss, 0);
        float mu = s * (1.f / 512.f);
        float rs = rsqrtf(ss * (1.f / 512.f) - mu * mu + 1e-5f);
        union { uint4 v; u16 s[8]; } ob;
        float xn[8];
        #pragma unroll
        for (int jj = 0; jj < 8; jj++) {
            xn[jj] = (xv[jj] - mu) * rs * b2f(gb.s[jj]) + b2f(bb.s[jj]);
            ob.s[jj] = f2b(xn[jj]);
        }
        ((uint4*)(x1 + (rbase + lr) * 512))[l] = ob.v;
        if (l == 0) {
            #pragma unroll
            for (int jj = 0; jj < 8; jj++) xs8[lr][jj] = xn[jj];
        }
    }
    __syncthreads();
    {
        int r = t >> 3, jj = t & 7;
        fqout[(rbase + r) * 8 + jj] = f2b(__cosf(xs8[r][jj] + tf[jj]));
    }
}

// ---------------- ln2: 1 row per wave, output dtype per flags[0] ----------------
__global__ __launch_bounds__(256) void ln2_kernel(
    const u16* __restrict__ z, const u16* __restrict__ g, const u16* __restrict__ b,
    void* __restrict__ out, const int* flags)
{
    const int t = threadIdx.x;
    const int wv = t >> 6, l = t & 63;
    const size_t row = (size_t)blockIdx.x * 4 + wv;

    union { uint4 v; u16 s[8]; } zb, gb, bb;
    zb.v = ((const uint4*)(z + row * 512))[l];
    gb.v = *(const uint4*)(g + l * 8);
    bb.v = *(const uint4*)(b + l * 8);
    float xv[8], s = 0.f, ss = 0.f;
    #pragma unroll
    for (int jj = 0; jj < 8; jj++) { xv[jj] = b2f(zb.s[jj]); s += xv[jj]; ss += xv[jj]*xv[jj]; }
    #pragma unroll
    for (int o = 32; o > 0; o >>= 1) { s += __shfl_down(s, o); ss += __shfl_down(ss, o); }
    s = __shfl(s, 0); ss = __shfl(ss, 0);
    float mu = s * (1.f / 512.f);
    float rs = rsqrtf(ss * (1.f / 512.f) - mu * mu + 1e-5f);
    float xn[8];
    #pragma unroll
    for (int jj = 0; jj < 8; jj++)
        xn[jj] = (xv[jj] - mu) * rs * b2f(gb.s[jj]) + b2f(bb.s[jj]);
    if (flags[0]) {
        float* po = (float*)out + row * 512 + l * 8;
        float4 o0{xn[0],xn[1],xn[2],xn[3]}, o1{xn[4],xn[5],xn[6],xn[7]};
        *(float4*)po = o0; *(float4*)(po + 4) = o1;
    } else {
        union { uint4 v; u16 s[8]; } ob;
        #pragma unroll
        for (int jj = 0; jj < 8; jj++) ob.s[jj] = f2b(xn[jj]);
        ((uint4*)((u16*)out + row * 512))[l] = ob.v;
    }
}

extern "C" void kernel_launch(void* const* d_in, const int* in_sizes, int n_in,
                              void* d_out, int out_size, void* d_ws, size_t ws_size,
                              hipStream_t stream)
{
    u16* ws16 = (u16*)d_ws;
    // ws (u16 elems): W [0,1332752) | flags @1332752 | fq @1332800 (262144)
    //                 x1 @1594944 (16.7M) | y1/z @18372160 (16.7M)  => ~70.3 MB total
    // q (cos(x+theta), bf16) ALIASES the x1 region: q live [qgen, gemm1); x1 written by ln1 after.
    u16* W     = ws16;
    int* flags = (int*)(ws16 + 1332752);
    u16* fq  = ws16 + 1332800;
    u16* x1  = ws16 + 1594944;
    u16* q   = x1;
    u16* y1  = ws16 + 18372160;
    u16* z   = y1;                  // y1 rows dead after ln1; z overwrites

    const u16*  wWc  = W;
    const u16*  wW2  = W + 262144;
    const u16*  wTa  = W + 1310720;
    const u16*  wBc  = W + 1311232;
    const u16*  wB2  = W + 1311744;
    const u16*  wW1  = W + 1312256;
    const u16*  wB1  = W + 1328640;
    const u16*  wG1  = W + 1330688;
    const u16*  wB1l = W + 1331200;
    const u16*  wG2  = W + 1331712;
    const u16*  wB2l = W + 1332224;
    const float* wTf = (const float*)(W + 1332736);

    probe_kernel<<<13, 256, 0, stream>>>(
        (const u16*)d_in[0], (const u16*)d_in[1], (const u16*)d_in[2],
        (const u16*)d_in[3], (const u16*)d_in[4], (const u16*)d_in[5],
        (const u16*)d_in[6], (const u16*)d_in[7], (const u16*)d_in[8],
        (const u16*)d_in[9], (const u16*)d_in[10], (const u16*)d_in[11],
        (const u16*)d_in[12],
        in_sizes[0], in_sizes[1], in_sizes[2], in_sizes[3], in_sizes[4],
        in_sizes[5], in_sizes[6], in_sizes[7], in_sizes[8], in_sizes[9],
        in_sizes[10], in_sizes[11], in_sizes[12], flags);

    convert_kernel<<<657, 256, 0, stream>>>(
        d_in[2], d_in[9], d_in[7], d_in[1], d_in[3], d_in[4], d_in[5],
        d_in[6], d_in[8], d_in[10], d_in[11], d_in[12], (u16*)W, flags);

    qgen_kernel<<<8192, 256, 0, stream>>>(d_in[0], wTa, q, flags);

    gemm1_fused<<<1024, 256, 0, stream>>>(
        q, d_in[0], wWc, wBc, y1, 256, flags);

    ln1_kernel<<<512, 512, 0, stream>>>(y1, wG1, wB1l, wTf, x1, fq);

    gemm2_fused<<<256, 512, 0, stream>>>(
        fq, wW1, wB1, wW2, wB2, x1, z, 256);

    ln2_kernel<<<8192, 256, 0, stream>>>(z, wG2, wB2l, d_out, flags);
}